// Round 2
// baseline (313.838 us; speedup 1.0000x reference)
//
#include <hip/hip_runtime.h>

#define N1 1000000
#define N2 131072
#define N3 16384
#define N4 2048
#define N5 256
#define C 48

// ---------------------------------------------------------------- zero ws
__global__ void zero_kernel(float4* __restrict__ p, int n4) {
    int i = blockIdx.x * blockDim.x + threadIdx.x;
    int stride = gridDim.x * blockDim.x;
    for (; i < n4; i += stride) p[i] = make_float4(0.f, 0.f, 0.f, 0.f);
}

// ------------------------------------------------- scatter-add (segment_sum)
// One thread per (row, channel) element of the source level.
// Coalesced source reads; atomicAdd into dst[parent[row]*C + c].
__global__ void scatter_add_kernel(const float* __restrict__ src,
                                   const int* __restrict__ parent,
                                   float* __restrict__ dst, int nrows) {
    int total = nrows * C;
    int stride = gridDim.x * blockDim.x;
    for (int e = blockIdx.x * blockDim.x + threadIdx.x; e < total; e += stride) {
        unsigned ue = (unsigned)e;
        unsigned r = ue / C;      // compiler emits magic-multiply
        unsigned c = ue - r * C;
        atomicAdd(&dst[(unsigned)parent[r] * C + c], src[e]);
    }
}

// ------------------------------------------------------- gather + argmax
__device__ __forceinline__ int argmax48(const float4* __restrict__ row) {
    float best = -__builtin_inff();
    int bi = 0;
#pragma unroll
    for (int i = 0; i < 12; ++i) {
        float4 v = row[i];
        if (v.x > best) { best = v.x; bi = 4 * i + 0; }
        if (v.y > best) { best = v.y; bi = 4 * i + 1; }
        if (v.z > best) { best = v.z; bi = 4 * i + 2; }
        if (v.w > best) { best = v.w; bi = 4 * i + 3; }
    }
    return bi;
}

__global__ void gather_argmax_kernel(const float4* __restrict__ f2,
                                     const float4* __restrict__ f3,
                                     const float4* __restrict__ f4,
                                     const float4* __restrict__ f5,
                                     const int* __restrict__ idx2,
                                     const int* __restrict__ idx3,
                                     const int* __restrict__ idx4,
                                     const int* __restrict__ idx5,
                                     int* __restrict__ out) {
    int p = blockIdx.x * blockDim.x + threadIdx.x;
    if (p >= N1) return;
    // C floats = 12 float4 per row
    out[0 * N1 + p] = argmax48(f2 + (unsigned)idx2[p] * 12u);
    out[1 * N1 + p] = argmax48(f3 + (unsigned)idx3[p] * 12u);
    out[2 * N1 + p] = argmax48(f4 + (unsigned)idx4[p] * 12u);
    out[3 * N1 + p] = argmax48(f5 + (unsigned)idx5[p] * 12u);
}

extern "C" void kernel_launch(void* const* d_in, const int* in_sizes, int n_in,
                              void* d_out, int out_size, void* d_ws, size_t ws_size,
                              hipStream_t stream) {
    const float* slabel  = (const float*)d_in[0];
    const int* parent2   = (const int*)d_in[1];
    const int* parent3   = (const int*)d_in[2];
    const int* parent4   = (const int*)d_in[3];
    const int* parent5   = (const int*)d_in[4];
    const int* idx2      = (const int*)d_in[5];
    const int* idx3      = (const int*)d_in[6];
    const int* idx4      = (const int*)d_in[7];
    const int* idx5      = (const int*)d_in[8];
    int* out = (int*)d_out;   // JAX argmax output dtype is int32

    // workspace layout: f2 | f3 | f4 | f5  (fp32, C=48 per row)
    float* f2 = (float*)d_ws;
    float* f3 = f2 + (size_t)N2 * C;
    float* f4 = f3 + (size_t)N3 * C;
    float* f5 = f4 + (size_t)N4 * C;
    const int total_floats = (N2 + N3 + N4 + N5) * C;   // 7,188,480
    const int total_f4 = total_floats / 4;

    const int BLK = 256;

    // 1) zero the accumulator tables (ws is poisoned / stale between calls)
    zero_kernel<<<2048, BLK, 0, stream>>>((float4*)d_ws, total_f4);

    // 2) chained segment sums (stream order provides the dependencies)
    scatter_add_kernel<<<2048, BLK, 0, stream>>>(slabel, parent2, f2, N1);
    scatter_add_kernel<<<2048, BLK, 0, stream>>>(f2, parent3, f3, N2);
    scatter_add_kernel<<<512,  BLK, 0, stream>>>(f3, parent4, f4, N3);
    scatter_add_kernel<<<128,  BLK, 0, stream>>>(f4, parent5, f5, N4);

    // 3) gather + argmax at every level, one thread per query point
    gather_argmax_kernel<<<(N1 + BLK - 1) / BLK, BLK, 0, stream>>>(
        (const float4*)f2, (const float4*)f3, (const float4*)f4, (const float4*)f5,
        idx2, idx3, idx4, idx5, out);
}

// Round 3
// 213.543 us; speedup vs baseline: 1.4697x; 1.4697x over previous
//
#include <hip/hip_runtime.h>

#define N1 1000000
#define N2 131072
#define N3 16384
#define N4 2048
#define N5 256
#define C 48
#define NROWS (N2 + N3 + N4 + N5)   // 149,504 table rows total

// ---------------------------------------------------------------- zero ws
__global__ void zero_kernel(float4* __restrict__ p, int n4) {
    int i = blockIdx.x * blockDim.x + threadIdx.x;
    int stride = gridDim.x * blockDim.x;
    for (; i < n4; i += stride) p[i] = make_float4(0.f, 0.f, 0.f, 0.f);
}

// ------------------------------------------------- scatter-add (segment_sum)
__global__ void scatter_add_kernel(const float* __restrict__ src,
                                   const int* __restrict__ parent,
                                   float* __restrict__ dst, int nrows) {
    int total = nrows * C;
    int stride = gridDim.x * blockDim.x;
    for (int e = blockIdx.x * blockDim.x + threadIdx.x; e < total; e += stride) {
        unsigned ue = (unsigned)e;
        unsigned r = ue / C;
        unsigned c = ue - r * C;
        atomicAdd(&dst[(unsigned)parent[r] * C + c], src[e]);
    }
}

// ------------------------------------------------------- per-row argmax
__device__ __forceinline__ int argmax48(const float4* __restrict__ row) {
    float best = -__builtin_inff();
    int bi = 0;
#pragma unroll
    for (int i = 0; i < 12; ++i) {
        float4 v = row[i];
        if (v.x > best) { best = v.x; bi = 4 * i + 0; }
        if (v.y > best) { best = v.y; bi = 4 * i + 1; }
        if (v.z > best) { best = v.z; bi = 4 * i + 2; }
        if (v.w > best) { best = v.w; bi = 4 * i + 3; }
    }
    return bi;
}

// One thread per table row over the CONCATENATED f2|f3|f4|f5 tables.
__global__ void row_argmax_kernel(const float4* __restrict__ tables,
                                  unsigned char* __restrict__ tab) {
    int r = blockIdx.x * blockDim.x + threadIdx.x;
    if (r >= NROWS) return;
    tab[r] = (unsigned char)argmax48(tables + (unsigned)r * 12u);
}

// ------------------------------------------- final gather of precomputed argmax
__global__ void final_gather_kernel(const unsigned char* __restrict__ tab2,
                                    const unsigned char* __restrict__ tab3,
                                    const unsigned char* __restrict__ tab4,
                                    const unsigned char* __restrict__ tab5,
                                    const int* __restrict__ idx2,
                                    const int* __restrict__ idx3,
                                    const int* __restrict__ idx4,
                                    const int* __restrict__ idx5,
                                    int* __restrict__ out) {
    int p = blockIdx.x * blockDim.x + threadIdx.x;
    if (p >= N1) return;
    out[0 * N1 + p] = (int)tab2[idx2[p]];
    out[1 * N1 + p] = (int)tab3[idx3[p]];
    out[2 * N1 + p] = (int)tab4[idx4[p]];
    out[3 * N1 + p] = (int)tab5[idx5[p]];
}

extern "C" void kernel_launch(void* const* d_in, const int* in_sizes, int n_in,
                              void* d_out, int out_size, void* d_ws, size_t ws_size,
                              hipStream_t stream) {
    const float* slabel  = (const float*)d_in[0];
    const int* parent2   = (const int*)d_in[1];
    const int* parent3   = (const int*)d_in[2];
    const int* parent4   = (const int*)d_in[3];
    const int* parent5   = (const int*)d_in[4];
    const int* idx2      = (const int*)d_in[5];
    const int* idx3      = (const int*)d_in[6];
    const int* idx4      = (const int*)d_in[7];
    const int* idx5      = (const int*)d_in[8];
    int* out = (int*)d_out;   // JAX argmax output dtype is int32

    // workspace layout: f2 | f3 | f4 | f5 (fp32, contiguous) | tab (uint8)
    float* f2 = (float*)d_ws;
    float* f3 = f2 + (size_t)N2 * C;
    float* f4 = f3 + (size_t)N3 * C;
    float* f5 = f4 + (size_t)N4 * C;
    unsigned char* tab = (unsigned char*)(f5 + (size_t)N5 * C);
    unsigned char* tab2 = tab;
    unsigned char* tab3 = tab2 + N2;
    unsigned char* tab4 = tab3 + N3;
    unsigned char* tab5 = tab4 + N4;

    const int total_floats = NROWS * C;     // 7,176,192
    const int total_f4 = total_floats / 4;

    const int BLK = 256;

    // 1) zero the accumulator tables (ws is poisoned / stale between calls)
    zero_kernel<<<2048, BLK, 0, stream>>>((float4*)d_ws, total_f4);

    // 2) chained segment sums (stream order provides the dependencies)
    scatter_add_kernel<<<2048, BLK, 0, stream>>>(slabel, parent2, f2, N1);
    scatter_add_kernel<<<2048, BLK, 0, stream>>>(f2, parent3, f3, N2);
    scatter_add_kernel<<<512,  BLK, 0, stream>>>(f3, parent4, f4, N3);
    scatter_add_kernel<<<128,  BLK, 0, stream>>>(f4, parent5, f5, N4);

    // 3) per-row argmax over all four tables at once (tables are contiguous)
    row_argmax_kernel<<<(NROWS + BLK - 1) / BLK, BLK, 0, stream>>>(
        (const float4*)d_ws, tab);

    // 4) per-point gather of the precomputed argmax (tiny tables, L2-resident)
    final_gather_kernel<<<(N1 + BLK - 1) / BLK, BLK, 0, stream>>>(
        tab2, tab3, tab4, tab5, idx2, idx3, idx4, idx5, out);
}